// Round 12
// baseline (1355.819 us; speedup 1.0000x reference)
//
#include <hip/hip_runtime.h>
#include <math.h>

// ---------------- problem constants (NT=1, REAL=512 fixed by harness inputs) --
#define BB    2
#define SS    1024
#define EE    768
#define NH    8
#define DHD   96
#define NL    8
#define FFD   2048
#define VD    32000
#define REALC 512
#define MTOK  (BB*SS)     // 2048 rows for layer ops
#define MACTN (BB*REALC)  // 1024 rows for head ops
#define QKVW  (3*EE)      // 2304

// attention tiling
#define QB 64
#define KB 64
#define KS_LD 104   // K LDS row stride (elems)
#define VT_LD 72    // V^T LDS row stride
#define P_LD  72    // P LDS row stride

typedef __attribute__((ext_vector_type(8))) short bf16x8;
typedef __attribute__((ext_vector_type(4))) float f32x4;

static __device__ __forceinline__ float gelu_exact(float x) {
    return 0.5f * x * (1.0f + erff(x * 0.7071067811865476f));
}
static __device__ __forceinline__ unsigned short f2bf(float f) {
    unsigned int u = __builtin_bit_cast(unsigned int, f);
    unsigned int r = u + 0x7FFFu + ((u >> 16) & 1u);  // RNE (finite values only)
    return (unsigned short)(r >> 16);
}
static __device__ __forceinline__ float bf2f(unsigned short u) {
    union { unsigned int i; float f; } v; v.i = ((unsigned int)u) << 16; return v.f;
}

#define GLDS16(gp, lp) __builtin_amdgcn_global_load_lds( \
    (const __attribute__((address_space(1))) void*)(gp), \
    (__attribute__((address_space(3))) void*)(lp), 16, 0, 0)

// ---------------- batched fp32 -> bf16 convert of ALL weights + bias concat ----
#define CN0 (NL*QKVW*EE)
#define CN1 (NL*FFD*EE)
#define CN2 (NL*EE*FFD)
#define CN3 (FFD*EE)
#define CN4 (FFD*EE)
#define CN5 (VD*FFD)
#define CB0 (CN0/4)
#define CB1 (CB0 + CN1/4)
#define CB2 (CB1 + CN2/4)
#define CB3 (CB2 + CN3/4)
#define CB4 (CB3 + CN4/4)
#define CB5 (CB4 + CN5/4)         // 27,000,832 float4s total (= 256*105472)

__global__ __launch_bounds__(256) void convall_kernel(
    const float* __restrict__ s0, const float* __restrict__ s1,
    const float* __restrict__ s2, const float* __restrict__ s3,
    const float* __restrict__ s4, const float* __restrict__ s5,
    unsigned short* __restrict__ dst,
    const float* __restrict__ bp1, const float* __restrict__ bv1,
    float* __restrict__ bias_cat) {
    int i = blockIdx.x * 256 + threadIdx.x;     // float4 index
    if (i >= CB5) {                             // tail: bias concat (1024 f4)
        int j = i - CB5;
        if (j < 1024) {
            float4 v = (j < 512) ? ((const float4*)bp1)[j] : ((const float4*)bv1)[j - 512];
            ((float4*)bias_cat)[j] = v;
        }
        return;
    }
    const float* src;
    int loc;
    if      (i < CB0) { src = s0; loc = i; }
    else if (i < CB1) { src = s1; loc = i - CB0; }
    else if (i < CB2) { src = s2; loc = i - CB1; }
    else if (i < CB3) { src = s3; loc = i - CB2; }
    else if (i < CB4) { src = s4; loc = i - CB3; }
    else              { src = s5; loc = i - CB4; }
    float4 v = ((const float4*)src)[loc];
    ushort4 o;
    o.x = f2bf(v.x); o.y = f2bf(v.y); o.z = f2bf(v.z); o.w = f2bf(v.w);
    ((ushort4*)dst)[i] = o;
}

// ---------------- embed: h = x + pe(r) + tpe(p), dual fp32+bf16 out -------------
__global__ __launch_bounds__(256) void embed_kernel(const float* __restrict__ x,
                                                    const float* __restrict__ tpe,
                                                    float* __restrict__ h,
                                                    unsigned short* __restrict__ hb) {
    int idx = blockIdx.x * 256 + threadIdx.x;   // over MTOK*EE
    if (idx >= MTOK * EE) return;
    int e = idx % EE;
    int tok = idx / EE;          // b*SS + s
    int s = tok & (SS - 1);
    int r = s >> 1;              // s / bs
    int p = s & 1;               // s % bs
    int k2 = (e >> 1) * 2;
    float div = expf((float)k2 * (-9.210340371976184f / (float)EE)); // ln(10000)
    float ang = (float)r * div;
    float pe = (e & 1) ? cosf(ang) : sinf(ang);
    float v = x[idx] + pe + tpe[p * EE + e];
    h[idx] = v;
    hb[idx] = f2bf(v);
}

// ---------------- bf16 MFMA GEMM: 64x128 tile, BK=32, dbuf, swizzled -----------
// R7 known-good. MODE 0: fp32 out.  MODE 1: qkv (q/k -> Cb, v -> CvT^T).
// MODE 3: bf16 out + GELU.
template<int MODE>
__global__ __launch_bounds__(256) void gemm64_kernel(
    const unsigned short* __restrict__ A, const unsigned short* __restrict__ W,
    const float* __restrict__ bias, float* __restrict__ Cf,
    unsigned short* __restrict__ Cb, unsigned short* __restrict__ CvT,
    int M, int N, int K, int ldc) {
    __shared__ unsigned short As[2][64 * 32];
    __shared__ unsigned short Bs[2][128 * 32];
    const int bm = blockIdx.y * 64;
    const int bn = blockIdx.x * 128;
    const int t = threadIdx.x;
    const int w = t >> 6;
    const int lane = t & 63;
    const int wm = (w >> 1) * 32;
    const int wn = (w & 1) * 64;
    f32x4 acc[2][4] = {};

    const int sr   = t >> 2;              // 0..63
    const int skey = (t >> 3) & 3;        // (row>>1)&3
    const int scol = ((t & 3) ^ skey) * 8;
    const unsigned short* gA = A + (size_t)(bm + sr) * K + scol;
    const unsigned short* gB = W + (size_t)(bn + sr) * K + scol;

    const int lc  = lane & 15;
    const int lr4 = lane >> 4;
    const int sl  = (lr4 ^ ((lc >> 1) & 3)) * 8;

    const int nsteps = K >> 5;
    GLDS16(gA,                  &As[0][w * 512]);
    GLDS16(gB,                  &Bs[0][w * 512]);
    GLDS16(gB + (size_t)64 * K, &Bs[0][2048 + w * 512]);
    __syncthreads();
    for (int kt = 0; kt < nsteps; ++kt) {
        const int cur = kt & 1;
        if (kt + 1 < nsteps) {
            const int k0 = (kt + 1) << 5;
            GLDS16(gA + k0,                  &As[cur ^ 1][w * 512]);
            GLDS16(gB + k0,                  &Bs[cur ^ 1][w * 512]);
            GLDS16(gB + (size_t)64 * K + k0, &Bs[cur ^ 1][2048 + w * 512]);
        }
        bf16x8 a[2], b[4];
#pragma unroll
        for (int mi = 0; mi < 2; ++mi)
            a[mi] = *(const bf16x8*)&As[cur][(wm + mi * 16 + lc) * 32 + sl];
#pragma unroll
        for (int ni = 0; ni < 4; ++ni)
            b[ni] = *(const bf16x8*)&Bs[cur][(wn + ni * 16 + lc) * 32 + sl];
#pragma unroll
        for (int mi = 0; mi < 2; ++mi)
#pragma unroll
            for (int ni = 0; ni < 4; ++ni)
                acc[mi][ni] = __builtin_amdgcn_mfma_f32_16x16x32_bf16(
                    a[mi], b[ni], acc[mi][ni], 0, 0, 0);
        __syncthreads();   // drains vmcnt (prefetch) + guards buf reuse
    }

    const bool vpart = (MODE == 1) && (bn >= 2 * EE);   // uniform per block
#pragma unroll
    for (int mi = 0; mi < 2; ++mi) {
#pragma unroll
        for (int ni = 0; ni < 4; ++ni) {
            const int c = bn + wn + ni * 16 + lc;
            const float bv = bias[c];
            const int rwb = bm + wm + mi * 16 + lr4 * 4;
            if (vpart) {
                ushort4 pk;
                pk.x = f2bf(acc[mi][ni][0] + bv);
                pk.y = f2bf(acc[mi][ni][1] + bv);
                pk.z = f2bf(acc[mi][ni][2] + bv);
                pk.w = f2bf(acc[mi][ni][3] + bv);
                *(ushort4*)&CvT[(size_t)(c - 2 * EE) * MTOK + rwb] = pk;
            } else {
#pragma unroll
                for (int r = 0; r < 4; ++r) {
                    float v = acc[mi][ni][r] + bv;
                    if (MODE == 3) {
                        v = gelu_exact(v);
                        Cb[(size_t)(rwb + r) * ldc + c] = f2bf(v);
                    } else if (MODE == 1) {
                        Cb[(size_t)(rwb + r) * ldc + c] = f2bf(v);
                    } else {
                        Cf[(size_t)(rwb + r) * ldc + c] = v;
                    }
                }
            }
        }
    }
}

// ---------------- policy GEMM: 128x256 tile, BK=64 dbuf, 4-phase interleave ----
// 8-phase-template granularity (T3+T4+T5): 512 threads / 8 waves (wave 64x64),
// per phase {ds-reads || glds prefetch || raw barrier || setprio+8 MFMA || raw
// barrier}; ONE __syncthreads per K-tile (its implicit vmcnt(0) drains loads
// issued 2-3 phases earlier -> latency covered). Accumulation order identical
// to the 1-phase version (bitwise-same output).
__global__ __launch_bounds__(512, 2) void gemm_policy_kernel(
    const unsigned short* __restrict__ A, const unsigned short* __restrict__ W,
    const float* __restrict__ bias, float* __restrict__ C, int lda) {
    const int id = blockIdx.x;
    const int xcd = id & 7;
    const int rest = id >> 3;
    const int mt = rest & 7;                 // 0..7   M-tile
    const int ntile = (rest >> 3) * 8 + xcd; // 0..127 N-tile
    if (ntile >= VD / 256) return;           // uniform early-exit (24 idle blocks)
    const int bm = mt * 128;
    const int bn = ntile * 256;
    const int K = FFD;

    __shared__ unsigned short As[2][128 * 64];   // 32 KB
    __shared__ unsigned short Bs[2][256 * 64];   // 64 KB
    const int t = threadIdx.x;        // 0..511
    const int w = t >> 6;             // 0..7
    const int lane = t & 63;
    const int wm = (w >> 2) * 64;     // 2 M-waves
    const int wn = (w & 3) * 64;      // 4 N-waves
    f32x4 acc[4][4] = {};

    // staging: thread t -> row t>>3 (0..63 per issue group), slot t&7;
    // global source slot inverse-swizzled by row&7 (same scheme as before)
    const int srow = t >> 3;
    const int scol = ((t & 7) ^ (srow & 7)) * 8;
    const unsigned short* gA = A + (size_t)(bm + srow) * lda + scol;
    const unsigned short* gB = W + (size_t)(bn + srow) * K + scol;
    const int lwb = (w * 8) * 64;     // wave-uniform LDS base (elems)

    const int lc  = lane & 15;
    const int lr4 = lane >> 4;
    const int key8 = lc & 7;          // fragment-row swizzle key

#define PSTG_A(buf, k0) do { \
    GLDS16(gA + (k0),                    &As[buf][lwb]); \
    GLDS16(gA + (size_t)64 * lda + (k0), &As[buf][64 * 64 + lwb]); } while (0)
#define PSTG_B01(buf, k0) do { \
    GLDS16(gB + (k0),                    &Bs[buf][lwb]); \
    GLDS16(gB + (size_t)64 * K + (k0),   &Bs[buf][64 * 64 + lwb]); } while (0)
#define PSTG_B23(buf, k0) do { \
    GLDS16(gB + (size_t)128 * K + (k0),  &Bs[buf][128 * 64 + lwb]); \
    GLDS16(gB + (size_t)192 * K + (k0),  &Bs[buf][192 * 64 + lwb]); } while (0)

    PSTG_A(0, 0); PSTG_B01(0, 0); PSTG_B23(0, 0);
    __syncthreads();

    for (int kt = 0; kt < K / 64; ++kt) {
        const int cur = kt & 1;
        const unsigned short* Ac = As[cur];
        const unsigned short* Bc = Bs[cur];
        const int kn = (kt + 1) << 6;
        const bool pf = (kt + 1 < K / 64);
        bf16x8 a[4][2], b[4][2];
        // ---- phase 0: read a[0..1],b[0..1]; prefetch A(next); MFMA q(0,0)
#pragma unroll
        for (int mi = 0; mi < 2; ++mi)
#pragma unroll
            for (int ks = 0; ks < 2; ++ks)
                a[mi][ks] = *(const bf16x8*)&Ac[(wm + mi * 16 + lc) * 64 + ((ks * 4 + lr4) ^ key8) * 8];
#pragma unroll
        for (int ni = 0; ni < 2; ++ni)
#pragma unroll
            for (int ks = 0; ks < 2; ++ks)
                b[ni][ks] = *(const bf16x8*)&Bc[(wn + ni * 16 + lc) * 64 + ((ks * 4 + lr4) ^ key8) * 8];
        if (pf) PSTG_A(cur ^ 1, kn);
        __builtin_amdgcn_s_barrier();
        __builtin_amdgcn_s_setprio(1);
#pragma unroll
        for (int mi = 0; mi < 2; ++mi)
#pragma unroll
            for (int ni = 0; ni < 2; ++ni)
#pragma unroll
                for (int ks = 0; ks < 2; ++ks)
                    acc[mi][ni] = __builtin_amdgcn_mfma_f32_16x16x32_bf16(
                        a[mi][ks], b[ni][ks], acc[mi][ni], 0, 0, 0);
        __builtin_amdgcn_s_setprio(0);
        __builtin_amdgcn_s_barrier();
        // ---- phase 1: read b[2..3]; prefetch B01; MFMA q(0,1)
#pragma unroll
        for (int ni = 2; ni < 4; ++ni)
#pragma unroll
            for (int ks = 0; ks < 2; ++ks)
                b[ni][ks] = *(const bf16x8*)&Bc[(wn + ni * 16 + lc) * 64 + ((ks * 4 + lr4) ^ key8) * 8];
        if (pf) PSTG_B01(cur ^ 1, kn);
        __builtin_amdgcn_s_barrier();
        __builtin_amdgcn_s_setprio(1);
#pragma unroll
        for (int mi = 0; mi < 2; ++mi)
#pragma unroll
            for (int ni = 2; ni < 4; ++ni)
#pragma unroll
                for (int ks = 0; ks < 2; ++ks)
                    acc[mi][ni] = __builtin_amdgcn_mfma_f32_16x16x32_bf16(
                        a[mi][ks], b[ni][ks], acc[mi][ni], 0, 0, 0);
        __builtin_amdgcn_s_setprio(0);
        __builtin_amdgcn_s_barrier();
        // ---- phase 2: read a[2..3]; prefetch B23; MFMA q(1,1)
#pragma unroll
        for (int mi = 2; mi < 4; ++mi)
#pragma unroll
            for (int ks = 0; ks < 2; ++ks)
                a[mi][ks] = *(const bf16x8*)&Ac[(wm + mi * 16 + lc) * 64 + ((ks * 4 + lr4) ^ key8) * 8];
        if (pf) PSTG_B23(cur ^ 1, kn);
        __builtin_amdgcn_s_barrier();
        __builtin_amdgcn_s_setprio(1);
#pragma unroll
        for (int mi = 2; mi < 4; ++mi)
#pragma unroll
            for (int ni = 2; ni < 4; ++ni)
#pragma unroll
                for (int ks = 0; ks < 2; ++ks)
                    acc[mi][ni] = __builtin_amdgcn_mfma_f32_16x16x32_bf16(
                        a[mi][ks], b[ni][ks], acc[mi][ni], 0, 0, 0);
        __builtin_amdgcn_s_setprio(0);
        __builtin_amdgcn_s_barrier();
        // ---- phase 3: MFMA q(1,0); tile-end full sync (drains vmcnt/lgkm)
        __builtin_amdgcn_s_setprio(1);
#pragma unroll
        for (int mi = 2; mi < 4; ++mi)
#pragma unroll
            for (int ni = 0; ni < 2; ++ni)
#pragma unroll
                for (int ks = 0; ks < 2; ++ks)
                    acc[mi][ni] = __builtin_amdgcn_mfma_f32_16x16x32_bf16(
                        a[mi][ks], b[ni][ks], acc[mi][ni], 0, 0, 0);
        __builtin_amdgcn_s_setprio(0);
        __syncthreads();
    }
#undef PSTG_A
#undef PSTG_B01
#undef PSTG_B23
#pragma unroll
    for (int mi = 0; mi < 4; ++mi) {
#pragma unroll
        for (int ni = 0; ni < 4; ++ni) {
            const int c = bn + wn + ni * 16 + lc;
            const float bv = bias[c];
            const int rwb = bm + wm + mi * 16 + lr4 * 4;
#pragma unroll
            for (int r = 0; r < 4; ++r)
                C[(size_t)(rwb + r) * VD + c] = acc[mi][ni][r] + bv;
        }
    }
}

// ---------------- MFMA flash attention, K/V double-buffered (async-STAGE) ------
__global__ __launch_bounds__(256) void attn_mfma_kernel(
    const unsigned short* __restrict__ qkvb,   // [2048][2304] bf16 (v region unused)
    const unsigned short* __restrict__ vT,     // [768][2048] bf16
    float* __restrict__ o) {                   // [2048][768]
    __shared__ unsigned short Ks[2][KB * KS_LD];
    __shared__ unsigned short VTs[2][DHD * VT_LD];
    __shared__ unsigned short Ps[QB * P_LD];

    const int bq = blockIdx.x * QB;
    const int hh = blockIdx.y & 7;
    const int b  = blockIdx.y >> 3;
    const int t = threadIdx.x;
    const int w = t >> 6;
    const int lane = t & 63;
    const int lr = lane >> 4;       // 0..3
    const int lc = lane & 15;       // 0..15
    const float scale = 0.10206207261596577f; // 1/sqrt(96)

    const unsigned short* gK[3];
    const unsigned short* gV[3];
    int kwr[3], vwr[3];
#pragma unroll
    for (int it = 0; it < 3; ++it) {
        int flat = it * 256 + t;            // 0..767
        int kr = flat / 12;                 // 0..63
        int d8 = (flat % 12) * 8;           // 0..88
        int d  = flat >> 3;                 // 0..95
        int k8 = (flat & 7) * 8;            // 0..56
        gK[it] = qkvb + (size_t)(b * SS + kr) * QKVW + EE + hh * DHD + d8;
        gV[it] = vT + (size_t)(hh * DHD + d) * MTOK + b * SS + k8;
        kwr[it] = kr * KS_LD + d8;
        vwr[it] = d * VT_LD + k8;
    }

    bf16x8 qa[3];
    {
        const unsigned short* qrow = qkvb + (size_t)(b * SS + bq + w * 16 + lc) * QKVW + hh * DHD;
#pragma unroll
        for (int ks = 0; ks < 3; ++ks)
            qa[ks] = *(const bf16x8*)(qrow + ks * 32 + lr * 8);
    }

    f32x4 acc_o[6] = {};
    float m_st[4], l_st[4];
#pragma unroll
    for (int r = 0; r < 4; ++r) { m_st[r] = -1e30f; l_st[r] = 0.f; }
    const int q_row = lr << 2;
    const int qbase = bq + w * 16 + q_row;

    bf16x8 kst[3], vst[3];
#pragma unroll
    for (int it = 0; it < 3; ++it) {
        kst[it] = *(const bf16x8*)gK[it];
        vst[it] = *(const bf16x8*)gV[it];
    }
#pragma unroll
    for (int it = 0; it < 3; ++it) {
        *(bf16x8*)&Ks[0][kwr[it]] = kst[it];
        *(bf16x8*)&VTs[0][vwr[it]] = vst[it];
    }
    __syncthreads();

    const int NTILE = SS / KB;   // 16
    for (int kt = 0; kt < NTILE; ++kt) {
        const int cur = kt & 1;
        if (kt + 1 < NTILE) {
#pragma unroll
            for (int it = 0; it < 3; ++it) {
                kst[it] = *(const bf16x8*)(gK[it] + (size_t)(kt + 1) * KB * QKVW);
                vst[it] = *(const bf16x8*)(gV[it] + (kt + 1) * KB);
            }
        }

        f32x4 sfr[4] = {};
#pragma unroll
        for (int nf = 0; nf < 4; ++nf) {
#pragma unroll
            for (int ks = 0; ks < 3; ++ks) {
                bf16x8 kb = *(const bf16x8*)&Ks[cur][(nf * 16 + lc) * KS_LD + ks * 32 + lr * 8];
                sfr[nf] = __builtin_amdgcn_mfma_f32_16x16x32_bf16(qa[ks], kb, sfr[nf], 0, 0, 0);
            }
        }
        const int kbase = kt * KB;
#pragma unroll
        for (int nf = 0; nf < 4; ++nf) {
            const int k = kbase + nf * 16 + lc;
            const bool kodd = (k & 1);
#pragma unroll
            for (int r = 0; r < 4; ++r) {
                const int q = qbase + r;
                bool allowed = kodd ? (q == k) : (q >= k);
                sfr[nf][r] = sfr[nf][r] * scale + (allowed ? 0.f : 1.f);
            }
        }
        float corr[4];
#pragma unroll
        for (int r = 0; r < 4; ++r) {
            float v = fmaxf(fmaxf(sfr[0][r], sfr[1][r]), fmaxf(sfr[2][r], sfr[3][r]));
            v = fmaxf(v, __shfl_xor(v, 1)); v = fmaxf(v, __shfl_xor(v, 2));
            v = fmaxf(v, __shfl_xor(v, 4)); v = fmaxf(v, __shfl_xor(v, 8));
            float mn = fmaxf(m_st[r], v);
            corr[r] = __expf(m_st[r] - mn);
            m_st[r] = mn;
        }
        float rsum[4] = {0.f, 0.f, 0.f, 0.f};
#pragma unroll
        for (int nf = 0; nf < 4; ++nf) {
#pragma unroll
            for (int r = 0; r < 4; ++r) {
                float p = __expf(sfr[nf][r] - m_st[r]);
                rsum[r] += p;
                Ps[(w * 16 + q_row + r) * P_LD + nf * 16 + lc] = f2bf(p);
            }
        }
#pragma unroll
        for (int r = 0; r < 4; ++r) {
            float v = rsum[r];
            v += __shfl_xor(v, 1); v += __shfl_xor(v, 2);
            v += __shfl_xor(v, 4); v += __shfl_xor(v, 8);
            l_st[r] = l_st[r] * corr[r] + v;
        }
#pragma unroll
        for (int nf = 0; nf < 6; ++nf)
#pragma unroll
            for (int r = 0; r < 4; ++r)
                acc_o[nf][r] *= corr[r];
#pragma unroll
        for (int ks2 = 0; ks2 < 2; ++ks2) {
            bf16x8 pa = *(const bf16x8*)&Ps[(w * 16 + lc) * P_LD + ks2 * 32 + lr * 8];
#pragma unroll
            for (int nf = 0; nf < 6; ++nf) {
                bf16x8 vb = *(const bf16x8*)&VTs[cur][(nf * 16 + lc) * VT_LD + ks2 * 32 + lr * 8];
                acc_o[nf] = __builtin_amdgcn_mfma_f32_16x16x32_bf16(pa, vb, acc_o[nf], 0, 0, 0);
            }
        }

        if (kt + 1 < NTILE) {
#pragma unroll
            for (int it = 0; it < 3; ++it) {
                *(bf16x8*)&Ks[cur ^ 1][kwr[it]] = kst[it];
                *(bf16x8*)&VTs[cur ^ 1][vwr[it]] = vst[it];
            }
        }
        __syncthreads();
    }
#pragma unroll
    for (int nf = 0; nf < 6; ++nf) {
#pragma unroll
        for (int r = 0; r < 4; ++r) {
            const int q = bq + w * 16 + q_row + r;
            o[(size_t)(b * SS + q) * EE + hh * DHD + nf * 16 + lc] = acc_o[nf][r] / l_st[r];
        }
    }
}

// ---------------- layernorm: wave-shfl reduce, ONE barrier ----------------------
template<bool GATHER>
__global__ __launch_bounds__(256) void ln_kernel(const float* __restrict__ a,
                                                 const float* __restrict__ res,
                                                 const float* __restrict__ g,
                                                 const float* __restrict__ beta,
                                                 float* __restrict__ outf,
                                                 unsigned short* __restrict__ outb) {
    __shared__ float rs[4], rs2[4];
    const int row = blockIdx.x;
    const int t = threadIdx.x;
    int src = row;
    if (GATHER) src = (row >> 9) * SS + ((row & 511) << 1) + 1; // act_idx = 2r+1
    const float* pa = a + (size_t)src * EE;
    const float* pr = res ? res + (size_t)src * EE : nullptr;
    float x[3];
    float s = 0.f, s2 = 0.f;
#pragma unroll
    for (int i = 0; i < 3; ++i) {
        int e = t + i * 256;
        float v = pa[e] + (pr ? pr[e] : 0.f);
        x[i] = v; s += v; s2 += v * v;
    }
#pragma unroll
    for (int m = 1; m < 64; m <<= 1) {
        s  += __shfl_xor(s, m);
        s2 += __shfl_xor(s2, m);
    }
    if ((t & 63) == 0) { rs[t >> 6] = s; rs2[t >> 6] = s2; }
    __syncthreads();
    const float S  = rs[0] + rs[1] + rs[2] + rs[3];
    const float S2 = rs2[0] + rs2[1] + rs2[2] + rs2[3];
    const float mean = S * (1.0f / EE);
    const float var  = S2 * (1.0f / EE) - mean * mean;
    const float rstd = 1.0f / sqrtf(var + 1e-5f);
#pragma unroll
    for (int i = 0; i < 3; ++i) {
        int e = t + i * 256;
        float v = (x[i] - mean) * rstd * g[e] + beta[e];
        if (isnan(v)) v = 0.f;  // nan_to_num
        if (outf) outf[(size_t)row * EE + e] = v;
        if (outb) outb[(size_t)row * EE + e] = f2bf(v);
    }
}

// ---------------- value head second GEMM (N=1), bf16 input (strided) -----------
__global__ __launch_bounds__(256) void value2_kernel(const unsigned short* __restrict__ v1,
                                                     const float* __restrict__ Wv2,
                                                     const float* __restrict__ bv2,
                                                     float* __restrict__ out, int ld) {
    __shared__ float red[4];
    const int row = blockIdx.x;
    const int t = threadIdx.x;
    const unsigned short* pr = v1 + (size_t)row * ld;
    float s = 0.f;
    for (int i = t; i < FFD; i += 256) s = fmaf(bf2f(pr[i]), Wv2[i], s);
#pragma unroll
    for (int m = 1; m < 64; m <<= 1) s += __shfl_xor(s, m);
    if ((t & 63) == 0) red[t >> 6] = s;
    __syncthreads();
    if (t == 0) out[row] = red[0] + red[1] + red[2] + red[3] + bv2[0];
}

// ---------------- launch --------------------------------------------------------
extern "C" void kernel_launch(void* const* d_in, const int* in_sizes, int n_in,
                              void* d_out, int out_size, void* d_ws, size_t ws_size,
                              hipStream_t stream) {
    const float* x    = (const float*)d_in[0];
    const float* tpe  = (const float*)d_in[1];
    const float* Wqkv = (const float*)d_in[2];
    const float* bqkv = (const float*)d_in[3];
    const float* W1   = (const float*)d_in[4];
    const float* b1   = (const float*)d_in[5];
    const float* W2   = (const float*)d_in[6];
    const float* b2   = (const float*)d_in[7];
    const float* g1   = (const float*)d_in[8];
    const float* be1  = (const float*)d_in[9];
    const float* g2   = (const float*)d_in[10];
    const float* be2  = (const float*)d_in[11];
    const float* gf   = (const float*)d_in[12];
    const float* bf   = (const float*)d_in[13];
    const float* Wp1  = (const float*)d_in[14];
    const float* bp1  = (const float*)d_in[15];
    const float* Wp2  = (const float*)d_in[16];
    const float* bp2  = (const float*)d_in[17];
    const float* Wv1  = (const float*)d_in[18];
    const float* bv1  = (const float*)d_in[19];
    const float* Wv2  = (const float*)d_in[20];
    const float* bv2  = (const float*)d_in[21];

    // ---- workspace layout ----
    float* ws  = (float*)d_ws;
    float* h   = ws;                        // 2048*768
    float* o   = h  + (size_t)MTOK * EE;    // 2048*768
    float* hc  = o  + (size_t)MTOK * EE;    // 2048*768
    float* ff2 = hc + (size_t)MTOK * EE;    // 2048*768
    float* bias_cat = ff2 + (size_t)MTOK * EE;  // 4096 (bp1 || bv1)
    unsigned short* bws = (unsigned short*)(bias_cat + 4096);
    unsigned short* h_bf    = bws;                                   // 2048*768
    unsigned short* hc_bf   = h_bf    + (size_t)MTOK * EE;           // 2048*768
    unsigned short* ff1_bf  = hc_bf   + (size_t)MTOK * EE;           // 2048*2048
    unsigned short* act_bf  = ff1_bf  + (size_t)MTOK * FFD;          // 1024*768
    unsigned short* p1v1_bf = act_bf  + (size_t)MACTN * EE;          // 1024*4096
    unsigned short* qkv_bf  = p1v1_bf + (size_t)MACTN * 2 * FFD;     // 2048*2304
    unsigned short* vT      = qkv_bf  + (size_t)MTOK * QKVW;         // 768*2048
    // weights: contiguous, order must match convall_kernel boundaries
    unsigned short* wq_all  = vT      + (size_t)EE * MTOK;           // 8*2304*768
    unsigned short* w1_all  = wq_all  + (size_t)CN0;                 // 8*2048*768
    unsigned short* w2_all  = w1_all  + (size_t)CN1;                 // 8*768*2048
    unsigned short* wp1_bf  = w2_all  + (size_t)CN2;                 // 2048*768
    unsigned short* wv1_bf  = wp1_bf  + (size_t)CN3;                 // 2048*768 (contig after wp1)
    unsigned short* wp2_bf  = wv1_bf  + (size_t)CN4;                 // 32000*2048
    (void)wv1_bf;

    float* pol = (float*)d_out;                       // 1024*32000
    float* val = (float*)d_out + (size_t)MACTN * VD;  // 1024

    const int C256 = 256;
#define NBLK(n) (((n) + 255) / 256)

    embed_kernel<<<NBLK(MTOK * EE), C256, 0, stream>>>(x, tpe, h, h_bf);

    // all weight converts + bias concat in ONE dispatch
    convall_kernel<<<CB5 / 256 + 4, C256, 0, stream>>>(
        Wqkv, W1, W2, Wp1, Wv1, Wp2, wq_all, bp1, bv1, bias_cat);

    for (int l = 0; l < NL; ++l) {
        gemm64_kernel<1><<<dim3(QKVW / 128, MTOK / 64), C256, 0, stream>>>(
            h_bf, wq_all + (size_t)l * QKVW * EE, bqkv + (size_t)l * QKVW,
            nullptr, qkv_bf, vT, MTOK, QKVW, EE, QKVW);
        attn_mfma_kernel<<<dim3(SS / QB, BB * NH), C256, 0, stream>>>(qkv_bf, vT, o);
        ln_kernel<false><<<MTOK, C256, 0, stream>>>(h, o, g1 + l * EE, be1 + l * EE, hc, hc_bf);
        gemm64_kernel<3><<<dim3(FFD / 128, MTOK / 64), C256, 0, stream>>>(
            hc_bf, w1_all + (size_t)l * FFD * EE, b1 + (size_t)l * FFD,
            nullptr, ff1_bf, nullptr, MTOK, FFD, EE, FFD);
        gemm64_kernel<0><<<dim3(EE / 128, MTOK / 64), C256, 0, stream>>>(
            ff1_bf, w2_all + (size_t)l * EE * FFD, b2 + (size_t)l * EE,
            ff2, nullptr, nullptr, MTOK, EE, FFD, EE);
        ln_kernel<false><<<MTOK, C256, 0, stream>>>(hc, ff2, g2 + l * EE, be2 + l * EE, h, h_bf);
    }

    // final LN on the 1024 action rows (act_idx = 2r+1), bf16 out only
    ln_kernel<true><<<MACTN, C256, 0, stream>>>(h, nullptr, gf, bf, nullptr, act_bf);

    // heads: p1||v1 = gelu(act @ [Wp1;Wv1]^T + [bp1;bv1])  (one N=4096 GEMM)
    gemm64_kernel<3><<<dim3(2 * FFD / 128, MACTN / 64), C256, 0, stream>>>(
        act_bf, wp1_bf, bias_cat, nullptr, p1v1_bf, nullptr, MACTN, 2 * FFD, EE, 2 * FFD);

    // policy: pol = p1 @ Wp2^T + bp2 (lda = 4096), 512-thread 4-phase kernel
    gemm_policy_kernel<<<1024, 512, 0, stream>>>(p1v1_bf, wp2_bf, bp2, pol, 2 * FFD);

    // value: val = v1 @ Wv2^T + bv2 (v1 = cols 2048.. of p1v1)
    value2_kernel<<<MACTN, C256, 0, stream>>>(p1v1_bf + FFD, Wv2, bv2, val, 2 * FFD);
#undef NBLK
}

// Round 13
// 1278.775 us; speedup vs baseline: 1.0602x; 1.0602x over previous
//
#include <hip/hip_runtime.h>
#include <math.h>

// ---------------- problem constants (NT=1, REAL=512 fixed by harness inputs) --
#define BB    2
#define SS    1024
#define EE    768
#define NH    8
#define DHD   96
#define NL    8
#define FFD   2048
#define VD    32000
#define REALC 512
#define MTOK  (BB*SS)     // 2048 rows for layer ops
#define MACTN (BB*REALC)  // 1024 rows for head ops
#define QKVW  (3*EE)      // 2304

// attention tiling
#define QB 64
#define KB 64
#define KS_LD 104   // K LDS row stride (elems)
#define VT_LD 72    // V^T LDS row stride
#define P_LD  72    // P LDS row stride

typedef __attribute__((ext_vector_type(8))) short bf16x8;
typedef __attribute__((ext_vector_type(4))) float f32x4;

static __device__ __forceinline__ float gelu_exact(float x) {
    return 0.5f * x * (1.0f + erff(x * 0.7071067811865476f));
}
static __device__ __forceinline__ unsigned short f2bf(float f) {
    unsigned int u = __builtin_bit_cast(unsigned int, f);
    unsigned int r = u + 0x7FFFu + ((u >> 16) & 1u);  // RNE (finite values only)
    return (unsigned short)(r >> 16);
}
static __device__ __forceinline__ float bf2f(unsigned short u) {
    union { unsigned int i; float f; } v; v.i = ((unsigned int)u) << 16; return v.f;
}

#define GLDS16(gp, lp) __builtin_amdgcn_global_load_lds( \
    (const __attribute__((address_space(1))) void*)(gp), \
    (__attribute__((address_space(3))) void*)(lp), 16, 0, 0)

// ---------------- batched fp32 -> bf16 convert of ALL weights + bias concat ----
#define CN0 (NL*QKVW*EE)
#define CN1 (NL*FFD*EE)
#define CN2 (NL*EE*FFD)
#define CN3 (FFD*EE)
#define CN4 (FFD*EE)
#define CN5 (VD*FFD)
#define CB0 (CN0/4)
#define CB1 (CB0 + CN1/4)
#define CB2 (CB1 + CN2/4)
#define CB3 (CB2 + CN3/4)
#define CB4 (CB3 + CN4/4)
#define CB5 (CB4 + CN5/4)         // 27,000,832 float4s total (= 256*105472)

__global__ __launch_bounds__(256) void convall_kernel(
    const float* __restrict__ s0, const float* __restrict__ s1,
    const float* __restrict__ s2, const float* __restrict__ s3,
    const float* __restrict__ s4, const float* __restrict__ s5,
    unsigned short* __restrict__ dst,
    const float* __restrict__ bp1, const float* __restrict__ bv1,
    float* __restrict__ bias_cat) {
    int i = blockIdx.x * 256 + threadIdx.x;     // float4 index
    if (i >= CB5) {                             // tail: bias concat (1024 f4)
        int j = i - CB5;
        if (j < 1024) {
            float4 v = (j < 512) ? ((const float4*)bp1)[j] : ((const float4*)bv1)[j - 512];
            ((float4*)bias_cat)[j] = v;
        }
        return;
    }
    const float* src;
    int loc;
    if      (i < CB0) { src = s0; loc = i; }
    else if (i < CB1) { src = s1; loc = i - CB0; }
    else if (i < CB2) { src = s2; loc = i - CB1; }
    else if (i < CB3) { src = s3; loc = i - CB2; }
    else if (i < CB4) { src = s4; loc = i - CB3; }
    else              { src = s5; loc = i - CB4; }
    float4 v = ((const float4*)src)[loc];
    ushort4 o;
    o.x = f2bf(v.x); o.y = f2bf(v.y); o.z = f2bf(v.z); o.w = f2bf(v.w);
    ((ushort4*)dst)[i] = o;
}

// ---------------- embed: h = x + pe(r) + tpe(p), dual fp32+bf16 out -------------
__global__ __launch_bounds__(256) void embed_kernel(const float* __restrict__ x,
                                                    const float* __restrict__ tpe,
                                                    float* __restrict__ h,
                                                    unsigned short* __restrict__ hb) {
    int idx = blockIdx.x * 256 + threadIdx.x;   // over MTOK*EE
    if (idx >= MTOK * EE) return;
    int e = idx % EE;
    int tok = idx / EE;          // b*SS + s
    int s = tok & (SS - 1);
    int r = s >> 1;              // s / bs
    int p = s & 1;               // s % bs
    int k2 = (e >> 1) * 2;
    float div = expf((float)k2 * (-9.210340371976184f / (float)EE)); // ln(10000)
    float ang = (float)r * div;
    float pe = (e & 1) ? cosf(ang) : sinf(ang);
    float v = x[idx] + pe + tpe[p * EE + e];
    h[idx] = v;
    hb[idx] = f2bf(v);
}

// ---------------- bf16 MFMA GEMM: 64x128 tile, BK=32, dbuf, swizzled -----------
// R7 known-good. MODE 0: fp32 out.  MODE 1: qkv (q/k -> Cb, v -> CvT^T).
// MODE 3: bf16 out + GELU.
template<int MODE>
__global__ __launch_bounds__(256) void gemm64_kernel(
    const unsigned short* __restrict__ A, const unsigned short* __restrict__ W,
    const float* __restrict__ bias, float* __restrict__ Cf,
    unsigned short* __restrict__ Cb, unsigned short* __restrict__ CvT,
    int M, int N, int K, int ldc) {
    __shared__ unsigned short As[2][64 * 32];
    __shared__ unsigned short Bs[2][128 * 32];
    const int bm = blockIdx.y * 64;
    const int bn = blockIdx.x * 128;
    const int t = threadIdx.x;
    const int w = t >> 6;
    const int lane = t & 63;
    const int wm = (w >> 1) * 32;
    const int wn = (w & 1) * 64;
    f32x4 acc[2][4] = {};

    const int sr   = t >> 2;              // 0..63
    const int skey = (t >> 3) & 3;        // (row>>1)&3
    const int scol = ((t & 3) ^ skey) * 8;
    const unsigned short* gA = A + (size_t)(bm + sr) * K + scol;
    const unsigned short* gB = W + (size_t)(bn + sr) * K + scol;

    const int lc  = lane & 15;
    const int lr4 = lane >> 4;
    const int sl  = (lr4 ^ ((lc >> 1) & 3)) * 8;

    const int nsteps = K >> 5;
    GLDS16(gA,                  &As[0][w * 512]);
    GLDS16(gB,                  &Bs[0][w * 512]);
    GLDS16(gB + (size_t)64 * K, &Bs[0][2048 + w * 512]);
    __syncthreads();
    for (int kt = 0; kt < nsteps; ++kt) {
        const int cur = kt & 1;
        if (kt + 1 < nsteps) {
            const int k0 = (kt + 1) << 5;
            GLDS16(gA + k0,                  &As[cur ^ 1][w * 512]);
            GLDS16(gB + k0,                  &Bs[cur ^ 1][w * 512]);
            GLDS16(gB + (size_t)64 * K + k0, &Bs[cur ^ 1][2048 + w * 512]);
        }
        bf16x8 a[2], b[4];
#pragma unroll
        for (int mi = 0; mi < 2; ++mi)
            a[mi] = *(const bf16x8*)&As[cur][(wm + mi * 16 + lc) * 32 + sl];
#pragma unroll
        for (int ni = 0; ni < 4; ++ni)
            b[ni] = *(const bf16x8*)&Bs[cur][(wn + ni * 16 + lc) * 32 + sl];
#pragma unroll
        for (int mi = 0; mi < 2; ++mi)
#pragma unroll
            for (int ni = 0; ni < 4; ++ni)
                acc[mi][ni] = __builtin_amdgcn_mfma_f32_16x16x32_bf16(
                    a[mi], b[ni], acc[mi][ni], 0, 0, 0);
        __syncthreads();   // drains vmcnt (prefetch) + guards buf reuse
    }

    const bool vpart = (MODE == 1) && (bn >= 2 * EE);   // uniform per block
#pragma unroll
    for (int mi = 0; mi < 2; ++mi) {
#pragma unroll
        for (int ni = 0; ni < 4; ++ni) {
            const int c = bn + wn + ni * 16 + lc;
            const float bv = bias[c];
            const int rwb = bm + wm + mi * 16 + lr4 * 4;
            if (vpart) {
                ushort4 pk;
                pk.x = f2bf(acc[mi][ni][0] + bv);
                pk.y = f2bf(acc[mi][ni][1] + bv);
                pk.z = f2bf(acc[mi][ni][2] + bv);
                pk.w = f2bf(acc[mi][ni][3] + bv);
                *(ushort4*)&CvT[(size_t)(c - 2 * EE) * MTOK + rwb] = pk;
            } else {
#pragma unroll
                for (int r = 0; r < 4; ++r) {
                    float v = acc[mi][ni][r] + bv;
                    if (MODE == 3) {
                        v = gelu_exact(v);
                        Cb[(size_t)(rwb + r) * ldc + c] = f2bf(v);
                    } else if (MODE == 1) {
                        Cb[(size_t)(rwb + r) * ldc + c] = f2bf(v);
                    } else {
                        Cf[(size_t)(rwb + r) * ldc + c] = v;
                    }
                }
            }
        }
    }
}

// ---------------- policy GEMM: 128x256 tile, BK=64, 2-barrier + swizzle --------
// R7/R11 known-good (156us, MfmaUtil ~37%, conflicts 0). XCD-aware grid.
__global__ __launch_bounds__(256, 2) void gemm_policy_kernel(
    const unsigned short* __restrict__ A, const unsigned short* __restrict__ W,
    const float* __restrict__ bias, float* __restrict__ C, int lda) {
    const int id = blockIdx.x;
    const int xcd = id & 7;
    const int rest = id >> 3;
    const int mt = rest & 7;                 // 0..7   M-tile
    const int ntile = (rest >> 3) * 8 + xcd; // 0..127 N-tile
    if (ntile >= VD / 256) return;           // uniform early-exit (24 idle blocks)
    const int bm = mt * 128;
    const int bn = ntile * 256;
    const int K = FFD;

    __shared__ unsigned short As[128 * 64];
    __shared__ unsigned short Bs[256 * 64];
    const int t = threadIdx.x;
    const int w = t >> 6;
    const int lane = t & 63;
    const int wm = (w >> 1) * 64;
    const int wn = (w & 1) * 128;
    f32x4 acc[4][8] = {};

    const int rr8  = (w << 3) + (lane >> 3);
    const int scol = (((lane & 7) ^ ((lane >> 3) & 7))) * 8;
    const unsigned short* gA = A + (size_t)(bm + rr8) * lda + scol;
    const unsigned short* gB = W + (size_t)(bn + rr8) * K + scol;

    const int lc  = lane & 15;
    const int lr4 = lane >> 4;
    const int key8 = lc & 7;     // fragment-row swizzle key

    for (int k0 = 0; k0 < K; k0 += 64) {
        __syncthreads();
#pragma unroll
        for (int i = 0; i < 4; ++i)
            GLDS16(gA + (size_t)(i * 32) * lda + k0, &As[((w << 3) + i * 32) * 64]);
#pragma unroll
        for (int i = 0; i < 8; ++i)
            GLDS16(gB + (size_t)(i * 32) * K + k0, &Bs[((w << 3) + i * 32) * 64]);
        __syncthreads();
#pragma unroll
        for (int ks = 0; ks < 2; ++ks) {
            const int sl = ((ks * 4 + lr4) ^ key8) * 8;
            bf16x8 a[4], b[8];
#pragma unroll
            for (int mi = 0; mi < 4; ++mi)
                a[mi] = *(const bf16x8*)&As[(wm + mi * 16 + lc) * 64 + sl];
#pragma unroll
            for (int ni = 0; ni < 8; ++ni)
                b[ni] = *(const bf16x8*)&Bs[(wn + ni * 16 + lc) * 64 + sl];
#pragma unroll
            for (int mi = 0; mi < 4; ++mi)
#pragma unroll
                for (int ni = 0; ni < 8; ++ni)
                    acc[mi][ni] = __builtin_amdgcn_mfma_f32_16x16x32_bf16(
                        a[mi], b[ni], acc[mi][ni], 0, 0, 0);
        }
    }
#pragma unroll
    for (int mi = 0; mi < 4; ++mi) {
#pragma unroll
        for (int ni = 0; ni < 8; ++ni) {
            const int c = bn + wn + ni * 16 + lc;
            const float bv = bias[c];
            const int rwb = bm + wm + mi * 16 + lr4 * 4;
#pragma unroll
            for (int r = 0; r < 4; ++r)
                C[(size_t)(rwb + r) * VD + c] = acc[mi][ni][r] + bv;
        }
    }
}

// ---------------- MFMA flash attention, K/V double-buffered (async-STAGE) ------
__global__ __launch_bounds__(256) void attn_mfma_kernel(
    const unsigned short* __restrict__ qkvb,   // [2048][2304] bf16 (v region unused)
    const unsigned short* __restrict__ vT,     // [768][2048] bf16
    float* __restrict__ o) {                   // [2048][768]
    __shared__ unsigned short Ks[2][KB * KS_LD];
    __shared__ unsigned short VTs[2][DHD * VT_LD];
    __shared__ unsigned short Ps[QB * P_LD];

    const int bq = blockIdx.x * QB;
    const int hh = blockIdx.y & 7;
    const int b  = blockIdx.y >> 3;
    const int t = threadIdx.x;
    const int w = t >> 6;
    const int lane = t & 63;
    const int lr = lane >> 4;       // 0..3
    const int lc = lane & 15;       // 0..15
    const float scale = 0.10206207261596577f; // 1/sqrt(96)

    const unsigned short* gK[3];
    const unsigned short* gV[3];
    int kwr[3], vwr[3];
#pragma unroll
    for (int it = 0; it < 3; ++it) {
        int flat = it * 256 + t;            // 0..767
        int kr = flat / 12;                 // 0..63
        int d8 = (flat % 12) * 8;           // 0..88
        int d  = flat >> 3;                 // 0..95
        int k8 = (flat & 7) * 8;            // 0..56
        gK[it] = qkvb + (size_t)(b * SS + kr) * QKVW + EE + hh * DHD + d8;
        gV[it] = vT + (size_t)(hh * DHD + d) * MTOK + b * SS + k8;
        kwr[it] = kr * KS_LD + d8;
        vwr[it] = d * VT_LD + k8;
    }

    bf16x8 qa[3];
    {
        const unsigned short* qrow = qkvb + (size_t)(b * SS + bq + w * 16 + lc) * QKVW + hh * DHD;
#pragma unroll
        for (int ks = 0; ks < 3; ++ks)
            qa[ks] = *(const bf16x8*)(qrow + ks * 32 + lr * 8);
    }

    f32x4 acc_o[6] = {};
    float m_st[4], l_st[4];
#pragma unroll
    for (int r = 0; r < 4; ++r) { m_st[r] = -1e30f; l_st[r] = 0.f; }
    const int q_row = lr << 2;
    const int qbase = bq + w * 16 + q_row;

    bf16x8 kst[3], vst[3];
#pragma unroll
    for (int it = 0; it < 3; ++it) {
        kst[it] = *(const bf16x8*)gK[it];
        vst[it] = *(const bf16x8*)gV[it];
    }
#pragma unroll
    for (int it = 0; it < 3; ++it) {
        *(bf16x8*)&Ks[0][kwr[it]] = kst[it];
        *(bf16x8*)&VTs[0][vwr[it]] = vst[it];
    }
    __syncthreads();

    const int NTILE = SS / KB;   // 16
    for (int kt = 0; kt < NTILE; ++kt) {
        const int cur = kt & 1;
        if (kt + 1 < NTILE) {
#pragma unroll
            for (int it = 0; it < 3; ++it) {
                kst[it] = *(const bf16x8*)(gK[it] + (size_t)(kt + 1) * KB * QKVW);
                vst[it] = *(const bf16x8*)(gV[it] + (kt + 1) * KB);
            }
        }

        f32x4 sfr[4] = {};
#pragma unroll
        for (int nf = 0; nf < 4; ++nf) {
#pragma unroll
            for (int ks = 0; ks < 3; ++ks) {
                bf16x8 kb = *(const bf16x8*)&Ks[cur][(nf * 16 + lc) * KS_LD + ks * 32 + lr * 8];
                sfr[nf] = __builtin_amdgcn_mfma_f32_16x16x32_bf16(qa[ks], kb, sfr[nf], 0, 0, 0);
            }
        }
        const int kbase = kt * KB;
#pragma unroll
        for (int nf = 0; nf < 4; ++nf) {
            const int k = kbase + nf * 16 + lc;
            const bool kodd = (k & 1);
#pragma unroll
            for (int r = 0; r < 4; ++r) {
                const int q = qbase + r;
                bool allowed = kodd ? (q == k) : (q >= k);
                sfr[nf][r] = sfr[nf][r] * scale + (allowed ? 0.f : 1.f);
            }
        }
        float corr[4];
#pragma unroll
        for (int r = 0; r < 4; ++r) {
            float v = fmaxf(fmaxf(sfr[0][r], sfr[1][r]), fmaxf(sfr[2][r], sfr[3][r]));
            v = fmaxf(v, __shfl_xor(v, 1)); v = fmaxf(v, __shfl_xor(v, 2));
            v = fmaxf(v, __shfl_xor(v, 4)); v = fmaxf(v, __shfl_xor(v, 8));
            float mn = fmaxf(m_st[r], v);
            corr[r] = __expf(m_st[r] - mn);
            m_st[r] = mn;
        }
        float rsum[4] = {0.f, 0.f, 0.f, 0.f};
#pragma unroll
        for (int nf = 0; nf < 4; ++nf) {
#pragma unroll
            for (int r = 0; r < 4; ++r) {
                float p = __expf(sfr[nf][r] - m_st[r]);
                rsum[r] += p;
                Ps[(w * 16 + q_row + r) * P_LD + nf * 16 + lc] = f2bf(p);
            }
        }
#pragma unroll
        for (int r = 0; r < 4; ++r) {
            float v = rsum[r];
            v += __shfl_xor(v, 1); v += __shfl_xor(v, 2);
            v += __shfl_xor(v, 4); v += __shfl_xor(v, 8);
            l_st[r] = l_st[r] * corr[r] + v;
        }
#pragma unroll
        for (int nf = 0; nf < 6; ++nf)
#pragma unroll
            for (int r = 0; r < 4; ++r)
                acc_o[nf][r] *= corr[r];
#pragma unroll
        for (int ks2 = 0; ks2 < 2; ++ks2) {
            bf16x8 pa = *(const bf16x8*)&Ps[(w * 16 + lc) * P_LD + ks2 * 32 + lr * 8];
#pragma unroll
            for (int nf = 0; nf < 6; ++nf) {
                bf16x8 vb = *(const bf16x8*)&VTs[cur][(nf * 16 + lc) * VT_LD + ks2 * 32 + lr * 8];
                acc_o[nf] = __builtin_amdgcn_mfma_f32_16x16x32_bf16(pa, vb, acc_o[nf], 0, 0, 0);
            }
        }

        if (kt + 1 < NTILE) {
#pragma unroll
            for (int it = 0; it < 3; ++it) {
                *(bf16x8*)&Ks[cur ^ 1][kwr[it]] = kst[it];
                *(bf16x8*)&VTs[cur ^ 1][vwr[it]] = vst[it];
            }
        }
        __syncthreads();
    }
#pragma unroll
    for (int nf = 0; nf < 6; ++nf) {
#pragma unroll
        for (int r = 0; r < 4; ++r) {
            const int q = bq + w * 16 + q_row + r;
            o[(size_t)(b * SS + q) * EE + hh * DHD + nf * 16 + lc] = acc_o[nf][r] / l_st[r];
        }
    }
}

// ---------------- layernorm: wave-shfl reduce, ONE barrier ----------------------
template<bool GATHER>
__global__ __launch_bounds__(256) void ln_kernel(const float* __restrict__ a,
                                                 const float* __restrict__ res,
                                                 const float* __restrict__ g,
                                                 const float* __restrict__ beta,
                                                 float* __restrict__ outf,
                                                 unsigned short* __restrict__ outb) {
    __shared__ float rs[4], rs2[4];
    const int row = blockIdx.x;
    const int t = threadIdx.x;
    int src = row;
    if (GATHER) src = (row >> 9) * SS + ((row & 511) << 1) + 1; // act_idx = 2r+1
    const float* pa = a + (size_t)src * EE;
    const float* pr = res ? res + (size_t)src * EE : nullptr;
    float x[3];
    float s = 0.f, s2 = 0.f;
#pragma unroll
    for (int i = 0; i < 3; ++i) {
        int e = t + i * 256;
        float v = pa[e] + (pr ? pr[e] : 0.f);
        x[i] = v; s += v; s2 += v * v;
    }
#pragma unroll
    for (int m = 1; m < 64; m <<= 1) {
        s  += __shfl_xor(s, m);
        s2 += __shfl_xor(s2, m);
    }
    if ((t & 63) == 0) { rs[t >> 6] = s; rs2[t >> 6] = s2; }
    __syncthreads();
    const float S  = rs[0] + rs[1] + rs[2] + rs[3];
    const float S2 = rs2[0] + rs2[1] + rs2[2] + rs2[3];
    const float mean = S * (1.0f / EE);
    const float var  = S2 * (1.0f / EE) - mean * mean;
    const float rstd = 1.0f / sqrtf(var + 1e-5f);
#pragma unroll
    for (int i = 0; i < 3; ++i) {
        int e = t + i * 256;
        float v = (x[i] - mean) * rstd * g[e] + beta[e];
        if (isnan(v)) v = 0.f;  // nan_to_num
        if (outf) outf[(size_t)row * EE + e] = v;
        if (outb) outb[(size_t)row * EE + e] = f2bf(v);
    }
}

// ---------------- value head second GEMM (N=1), bf16 input (strided) -----------
__global__ __launch_bounds__(256) void value2_kernel(const unsigned short* __restrict__ v1,
                                                     const float* __restrict__ Wv2,
                                                     const float* __restrict__ bv2,
                                                     float* __restrict__ out, int ld) {
    __shared__ float red[4];
    const int row = blockIdx.x;
    const int t = threadIdx.x;
    const unsigned short* pr = v1 + (size_t)row * ld;
    float s = 0.f;
    for (int i = t; i < FFD; i += 256) s = fmaf(bf2f(pr[i]), Wv2[i], s);
#pragma unroll
    for (int m = 1; m < 64; m <<= 1) s += __shfl_xor(s, m);
    if ((t & 63) == 0) red[t >> 6] = s;
    __syncthreads();
    if (t == 0) out[row] = red[0] + red[1] + red[2] + red[3] + bv2[0];
}

// ---------------- launch --------------------------------------------------------
extern "C" void kernel_launch(void* const* d_in, const int* in_sizes, int n_in,
                              void* d_out, int out_size, void* d_ws, size_t ws_size,
                              hipStream_t stream) {
    const float* x    = (const float*)d_in[0];
    const float* tpe  = (const float*)d_in[1];
    const float* Wqkv = (const float*)d_in[2];
    const float* bqkv = (const float*)d_in[3];
    const float* W1   = (const float*)d_in[4];
    const float* b1   = (const float*)d_in[5];
    const float* W2   = (const float*)d_in[6];
    const float* b2   = (const float*)d_in[7];
    const float* g1   = (const float*)d_in[8];
    const float* be1  = (const float*)d_in[9];
    const float* g2   = (const float*)d_in[10];
    const float* be2  = (const float*)d_in[11];
    const float* gf   = (const float*)d_in[12];
    const float* bf   = (const float*)d_in[13];
    const float* Wp1  = (const float*)d_in[14];
    const float* bp1  = (const float*)d_in[15];
    const float* Wp2  = (const float*)d_in[16];
    const float* bp2  = (const float*)d_in[17];
    const float* Wv1  = (const float*)d_in[18];
    const float* bv1  = (const float*)d_in[19];
    const float* Wv2  = (const float*)d_in[20];
    const float* bv2  = (const float*)d_in[21];

    // ---- workspace layout ----
    float* ws  = (float*)d_ws;
    float* h   = ws;                        // 2048*768
    float* o   = h  + (size_t)MTOK * EE;    // 2048*768
    float* hc  = o  + (size_t)MTOK * EE;    // 2048*768
    float* ff2 = hc + (size_t)MTOK * EE;    // 2048*768
    float* bias_cat = ff2 + (size_t)MTOK * EE;  // 4096 (bp1 || bv1)
    unsigned short* bws = (unsigned short*)(bias_cat + 4096);
    unsigned short* h_bf    = bws;                                   // 2048*768
    unsigned short* hc_bf   = h_bf    + (size_t)MTOK * EE;           // 2048*768
    unsigned short* ff1_bf  = hc_bf   + (size_t)MTOK * EE;           // 2048*2048
    unsigned short* act_bf  = ff1_bf  + (size_t)MTOK * FFD;          // 1024*768
    unsigned short* p1v1_bf = act_bf  + (size_t)MACTN * EE;          // 1024*4096
    unsigned short* qkv_bf  = p1v1_bf + (size_t)MACTN * 2 * FFD;     // 2048*2304
    unsigned short* vT      = qkv_bf  + (size_t)MTOK * QKVW;         // 768*2048
    // weights: contiguous, order must match convall_kernel boundaries
    unsigned short* wq_all  = vT      + (size_t)EE * MTOK;           // 8*2304*768
    unsigned short* w1_all  = wq_all  + (size_t)CN0;                 // 8*2048*768
    unsigned short* w2_all  = w1_all  + (size_t)CN1;                 // 8*768*2048
    unsigned short* wp1_bf  = w2_all  + (size_t)CN2;                 // 2048*768
    unsigned short* wv1_bf  = wp1_bf  + (size_t)CN3;                 // 2048*768 (contig after wp1)
    unsigned short* wp2_bf  = wv1_bf  + (size_t)CN4;                 // 32000*2048
    (void)wv1_bf;

    float* pol = (float*)d_out;                       // 1024*32000
    float* val = (float*)d_out + (size_t)MACTN * VD;  // 1024

    const int C256 = 256;
#define NBLK(n) (((n) + 255) / 256)

    embed_kernel<<<NBLK(MTOK * EE), C256, 0, stream>>>(x, tpe, h, h_bf);

    // all weight converts + bias concat in ONE dispatch
    convall_kernel<<<CB5 / 256 + 4, C256, 0, stream>>>(
        Wqkv, W1, W2, Wp1, Wv1, Wp2, wq_all, bp1, bv1, bias_cat);

    for (int l = 0; l < NL; ++l) {
        gemm64_kernel<1><<<dim3(QKVW / 128, MTOK / 64), C256, 0, stream>>>(
            h_bf, wq_all + (size_t)l * QKVW * EE, bqkv + (size_t)l * QKVW,
            nullptr, qkv_bf, vT, MTOK, QKVW, EE, QKVW);
        attn_mfma_kernel<<<dim3(SS / QB, BB * NH), C256, 0, stream>>>(qkv_bf, vT, o);
        ln_kernel<false><<<MTOK, C256, 0, stream>>>(h, o, g1 + l * EE, be1 + l * EE, hc, hc_bf);
        gemm64_kernel<3><<<dim3(FFD / 128, MTOK / 64), C256, 0, stream>>>(
            hc_bf, w1_all + (size_t)l * FFD * EE, b1 + (size_t)l * FFD,
            nullptr, ff1_bf, nullptr, MTOK, FFD, EE, FFD);
        gemm64_kernel<0><<<dim3(EE / 128, MTOK / 64), C256, 0, stream>>>(
            ff1_bf, w2_all + (size_t)l * EE * FFD, b2 + (size_t)l * EE,
            ff2, nullptr, nullptr, MTOK, EE, FFD, EE);
        ln_kernel<false><<<MTOK, C256, 0, stream>>>(hc, ff2, g2 + l * EE, be2 + l * EE, h, h_bf);
    }

    // final LN on the 1024 action rows (act_idx = 2r+1), bf16 out only
    ln_kernel<true><<<MACTN, C256, 0, stream>>>(h, nullptr, gf, bf, nullptr, act_bf);

    // heads: p1||v1 = gelu(act @ [Wp1;Wv1]^T + [bp1;bv1])  (one N=4096 GEMM)
    gemm64_kernel<3><<<dim3(2 * FFD / 128, MACTN / 64), C256, 0, stream>>>(
        act_bf, wp1_bf, bias_cat, nullptr, p1v1_bf, nullptr, MACTN, 2 * FFD, EE, 2 * FFD);

    // policy: pol = p1 @ Wp2^T + bp2 (lda = 4096)
    gemm_policy_kernel<<<1024, C256, 0, stream>>>(p1v1_bf, wp2_bf, bp2, pol, 2 * FFD);

    // value: val = v1 @ Wv2^T + bv2 (v1 = cols 2048.. of p1v1)
    value2_kernel<<<MACTN, C256, 0, stream>>>(p1v1_bf + FFD, Wv2, bv2, val, 2 * FFD);
#undef NBLK
}